// Round 3
// baseline (1041.379 us; speedup 1.0000x reference)
//
#include <hip/hip_runtime.h>
#include <math.h>

// Problem constants
#define S       2048
#define D       2048
#define EQ      2048   // N_Q_HEADS * HEAD_DIM
#define EK      512    // N_KV_HEADS * HEAD_DIM
#define ETOT    2560   // EQ + EK
#define NH      32
#define NKV     8
#define HD      64
#define KLEN    1024   // max(S*0.5, 2)

// Workspace layout (byte offsets)
#define OFF_COS   ((size_t)0)                    // [S][32] f32 = 256KB
#define OFF_SIN   ((size_t)(256u << 10))         // 256KB
#define OFF_QK    ((size_t)(1u << 20))           // [S][ETOT] f32 = 20MB
#define OFF_KT    ((size_t)(22u << 20))          // [NKV][64][S] f32 = 4MB
#define OFF_PART  ((size_t)(26u << 20))          // [1024][S] f32 = 8MB
#define OFF_VALS  ((size_t)(34u << 20))          // [S] f64 = 16KB
#define OFF_FLAGS ((size_t)((34u << 20) + (16u << 10)))   // [S] i32 = 8KB
#define OFF_ACCP  ((size_t)((34u << 20) + (32u << 10)))   // [32][S] f64 = 512KB

// ---------------------------------------------------------------------------
// 1) cos/sin tables in fp64 (fp32 arg reduction at pos~2047 gives ~1e-4 error,
//    j-correlated -> would destabilize the topk boundary).
__global__ void trig_kernel(float* __restrict__ cosT, float* __restrict__ sinT) {
  int idx = blockIdx.x * blockDim.x + threadIdx.x;  // S*32 = 65536
  int s = idx >> 5, i = idx & 31;
  double invf = 1.0 / pow(10000.0, (double)i / 32.0);
  double ang = (double)s * invf;
  cosT[idx] = (float)cos(ang);
  sinT[idx] = (float)sin(ang);
}

// ---------------------------------------------------------------------------
// 2) Fused gather + projection GEMM: C[s][e] = sum_d embed[ids[s]][d]*W[e][d]
//    64(s) x 128(e) tile, BK=16, 128 threads, 8x8 microtile.
//    LDS math: per kk per thread 64B read / 128 FLOP = 0.5 B/FLOP (balanced);
//    b-frag read as (g*4, g*4+64) quads -> 64 consecutive floats/wave = 2-way
//    bank aliasing (free). Per-element k-order identical to R2 (bit-stable).
#define BM 64
#define BN 128
#define BK 16
__global__ __launch_bounds__(128) void proj_gemm(
    const int* __restrict__ ids, const float* __restrict__ embed,
    const float* __restrict__ Wq, const float* __restrict__ Wk,
    float* __restrict__ C) {
  __shared__ float As[BK][BM + 4];   // 16 x 68
  __shared__ float Bs[BK][BN + 4];   // 16 x 132
  __shared__ int rowid[BM];
  const int t = threadIdx.x;           // 0..127
  const int col0 = blockIdx.x * BN;    // 20 col blocks
  const int row0 = blockIdx.y * BM;    // 32 row blocks
  const float* Wbase = (col0 < EQ) ? (Wq + (size_t)col0 * D)
                                   : (Wk + (size_t)(col0 - EQ) * D);
  if (t < BM) rowid[t] = ids[row0 + t];
  __syncthreads();

  // staging: A tile 64x16 = 256 quads, thread owns quads {t, t+128}
  //          B tile 128x16 = 512 quads, thread owns {t + 128*i, i<4}
  const int ak  = (t & 3) * 4;       // k quad offset
  const int am0 = t >> 2;            // 0..31
  const int am1 = am0 + 32;          // 32..63
  const float* Arow0 = embed + (size_t)rowid[am0] * D + ak;
  const float* Arow1 = embed + (size_t)rowid[am1] * D + ak;
  const float* Brow  = Wbase + (size_t)(t >> 2) * D + ak;  // rows +32i

  const int tm0 = (t >> 4) * 8;      // 8 s-rows
  const int tnA = (t & 15) * 4;      // cols tnA..+3 and tnA+64..+67
  float acc[8][8];
#pragma unroll
  for (int i = 0; i < 8; ++i)
#pragma unroll
    for (int j = 0; j < 8; ++j) acc[i][j] = 0.f;

  float4 a0 = *(const float4*)(Arow0);
  float4 a1 = *(const float4*)(Arow1);
  float4 b0 = *(const float4*)(Brow);
  float4 b1 = *(const float4*)(Brow + 32 * D);
  float4 b2 = *(const float4*)(Brow + 64 * D);
  float4 b3 = *(const float4*)(Brow + 96 * D);
  for (int k0 = 0; k0 < D; k0 += BK) {
    __syncthreads();
    As[ak + 0][am0] = a0.x; As[ak + 1][am0] = a0.y;
    As[ak + 2][am0] = a0.z; As[ak + 3][am0] = a0.w;
    As[ak + 0][am1] = a1.x; As[ak + 1][am1] = a1.y;
    As[ak + 2][am1] = a1.z; As[ak + 3][am1] = a1.w;
    const int bn = t >> 2;
    Bs[ak + 0][bn]      = b0.x; Bs[ak + 1][bn]      = b0.y;
    Bs[ak + 2][bn]      = b0.z; Bs[ak + 3][bn]      = b0.w;
    Bs[ak + 0][bn + 32] = b1.x; Bs[ak + 1][bn + 32] = b1.y;
    Bs[ak + 2][bn + 32] = b1.z; Bs[ak + 3][bn + 32] = b1.w;
    Bs[ak + 0][bn + 64] = b2.x; Bs[ak + 1][bn + 64] = b2.y;
    Bs[ak + 2][bn + 64] = b2.z; Bs[ak + 3][bn + 64] = b2.w;
    Bs[ak + 0][bn + 96] = b3.x; Bs[ak + 1][bn + 96] = b3.y;
    Bs[ak + 2][bn + 96] = b3.z; Bs[ak + 3][bn + 96] = b3.w;
    __syncthreads();
    // prefetch next k-tile (wraps on last iter; values discarded)
    const int kn = (k0 + BK) & (D - 1);
    a0 = *(const float4*)(Arow0 + kn);
    a1 = *(const float4*)(Arow1 + kn);
    b0 = *(const float4*)(Brow + kn);
    b1 = *(const float4*)(Brow + 32 * D + kn);
    b2 = *(const float4*)(Brow + 64 * D + kn);
    b3 = *(const float4*)(Brow + 96 * D + kn);
#pragma unroll
    for (int kk = 0; kk < BK; ++kk) {
      const float4 alo = *(const float4*)&As[kk][tm0];
      const float4 ahi = *(const float4*)&As[kk][tm0 + 4];
      const float4 blo = *(const float4*)&Bs[kk][tnA];
      const float4 bhi = *(const float4*)&Bs[kk][tnA + 64];
      const float av[8] = {alo.x, alo.y, alo.z, alo.w, ahi.x, ahi.y, ahi.z, ahi.w};
      const float bv[8] = {blo.x, blo.y, blo.z, blo.w, bhi.x, bhi.y, bhi.z, bhi.w};
#pragma unroll
      for (int i = 0; i < 8; ++i)
#pragma unroll
        for (int j = 0; j < 8; ++j) acc[i][j] = fmaf(av[i], bv[j], acc[i][j]);
    }
  }
#pragma unroll
  for (int i = 0; i < 8; ++i) {
    float* dst = C + (size_t)(row0 + tm0 + i) * ETOT + col0;
    *(float4*)(dst + tnA)      = make_float4(acc[i][0], acc[i][1], acc[i][2], acc[i][3]);
    *(float4*)(dst + tnA + 64) = make_float4(acc[i][4], acc[i][5], acc[i][6], acc[i][7]);
  }
}

// ---------------------------------------------------------------------------
// 3) RoPE on q, in place. One thread owns the (i, i+32) pair -> no race.
__global__ void rope_q_kernel(float* __restrict__ qk,
                              const float* __restrict__ cosT,
                              const float* __restrict__ sinT) {
  int idx = blockIdx.x * blockDim.x + threadIdx.x;  // S * NH * 32
  int s = idx >> 10;
  int rem = idx & 1023;
  int h = rem >> 5, i = rem & 31;
  float c = cosT[(s << 5) + i], sn = sinT[(s << 5) + i];
  float* p = qk + (size_t)s * ETOT + h * HD + i;
  float x1 = p[0], x2 = p[32];
  p[0]  = fmaf(x1, c, -x2 * sn);
  p[32] = fmaf(x2, c,  x1 * sn);
}

// 4) RoPE on k -> transposed kT[kv][d][s], via LDS tile so both the qk reads
//    and the kT writes are coalesced 256B rows. Same fp32 expressions as R2
//    (bit-identical kT).
__global__ __launch_bounds__(256) void rope_k_kernel(
    const float* __restrict__ qk, float* __restrict__ kT,
    const float* __restrict__ cosT, const float* __restrict__ sinT) {
  __shared__ float tile[64][65];   // [s][d], 65: bank-conflict-free columns
  __shared__ float ct[64][33];
  __shared__ float st[64][33];
  const int kv = blockIdx.x;       // 0..7
  const int s0 = blockIdx.y * 64;  // 0..2047
  const int t = threadIdx.x;
  {
    const int c = t & 63, r = t >> 6;  // r 0..3
#pragma unroll
    for (int p = 0; p < 16; ++p)
      tile[r + 4 * p][c] = qk[(size_t)(s0 + r + 4 * p) * ETOT + EQ + kv * HD + c];
  }
  {
    const int i = t & 31, r = t >> 5;  // r 0..7
#pragma unroll
    for (int p = 0; p < 8; ++p) {
      ct[r + 8 * p][i] = cosT[(s0 + r + 8 * p) * 32 + i];
      st[r + 8 * p][i] = sinT[(s0 + r + 8 * p) * 32 + i];
    }
  }
  __syncthreads();
  const int s = t & 63, dbase = t >> 6;  // dbase wave-uniform
#pragma unroll
  for (int p = 0; p < 16; ++p) {
    const int d = dbase + 4 * p;
    float v;
    if (d < 32) {
      const float c = ct[s][d], sn = st[s][d];
      const float x1 = tile[s][d], x2 = tile[s][d + 32];
      v = fmaf(x1, c, -x2 * sn);
    } else {
      const float c = ct[s][d - 32], sn = st[s][d - 32];
      const float x1 = tile[s][d - 32], x2 = tile[s][d];
      v = fmaf(x2, c, x1 * sn);
    }
    kT[(size_t)(kv * HD + d) * S + s0 + s] = v;
  }
}

// ---------------------------------------------------------------------------
// 5) Attention: block = (head, 64 rows) in 4 chunks of 16 rows. Each thread
//    owns 8 CONTIGUOUS columns (float4 loads) of all 2048; one-deep prefetch
//    on the d-loop. Unchanged from R2 (bit-identical).
__global__ __launch_bounds__(256) void attn_kernel(
    const float* __restrict__ qk, const float* __restrict__ kT,
    float* __restrict__ part) {
  const int h = blockIdx.x;    // 0..31
  const int sb = blockIdx.y;   // 0..31
  const int t = threadIdx.x;
  const float* kTh = kT + (size_t)(h >> 2) * HD * S;
  __shared__ float qlds[16][64];
  __shared__ float wred[4][16];
  float colacc[8];
#pragma unroll
  for (int u = 0; u < 8; ++u) colacc[u] = 0.f;
  const int c0 = t * 8;

  for (int ch = 0; ch < 4; ++ch) {
    const int row0 = sb * 64 + ch * 16;
    __syncthreads();
    {
      const int r = t >> 6, dd = t & 63;
#pragma unroll
      for (int rr = 0; rr < 4; ++rr)
        qlds[r + rr * 4][dd] = qk[(size_t)(row0 + r + rr * 4) * ETOT + h * HD + dd];
    }
    __syncthreads();
    float acc[16][8];
#pragma unroll
    for (int r = 0; r < 16; ++r)
#pragma unroll
      for (int u = 0; u < 8; ++u) acc[r][u] = 0.f;

    float4 ka = *(const float4*)(kTh + c0);
    float4 kb = *(const float4*)(kTh + c0 + 4);
    for (int d = 0; d < HD; ++d) {
      const int dn = (d + 1) & (HD - 1);   // wrap; last prefetch discarded
      const float4 na = *(const float4*)(kTh + (size_t)dn * S + c0);
      const float4 nb = *(const float4*)(kTh + (size_t)dn * S + c0 + 4);
      const float kv[8] = {ka.x, ka.y, ka.z, ka.w, kb.x, kb.y, kb.z, kb.w};
#pragma unroll
      for (int r = 0; r < 16; ++r) {
        const float qd = qlds[r][d];
#pragma unroll
        for (int u = 0; u < 8; ++u) acc[r][u] = fmaf(qd, kv[u], acc[r][u]);
      }
      ka = na; kb = nb;
    }
    float p[16];
#pragma unroll
    for (int r = 0; r < 16; ++r) {
      p[r] = 0.f;
#pragma unroll
      for (int u = 0; u < 8; ++u) {
        acc[r][u] = expf(acc[r][u]);
        p[r] += acc[r][u];
      }
    }
#pragma unroll
    for (int off = 32; off > 0; off >>= 1)
#pragma unroll
      for (int r = 0; r < 16; ++r) p[r] += __shfl_xor(p[r], off, 64);
    if ((t & 63) == 0) {
#pragma unroll
      for (int r = 0; r < 16; ++r) wred[t >> 6][r] = p[r];
    }
    __syncthreads();
#pragma unroll
    for (int r = 0; r < 16; ++r) {
      const float Z = wred[0][r] + wred[1][r] + wred[2][r] + wred[3][r];
      const float inv = 1.f / Z;
#pragma unroll
      for (int u = 0; u < 8; ++u) colacc[u] = fmaf(acc[r][u], inv, colacc[u]);
    }
  }
  const int b = h * 32 + sb;
  *(float4*)(part + (size_t)b * S + c0)     = make_float4(colacc[0], colacc[1], colacc[2], colacc[3]);
  *(float4*)(part + (size_t)b * S + c0 + 4) = make_float4(colacc[4], colacc[5], colacc[6], colacc[7]);
}

// ---------------------------------------------------------------------------
// 6) fp64 column totals, two stages for parallelism (fp64 reassociation only;
//    b ascending within group, groups ascending -> same left-to-right order).
__global__ void vals1_kernel(const float* __restrict__ part,
                             double* __restrict__ accp) {
  int j = blockIdx.x * 256 + threadIdx.x;  // 0..2047
  int g = blockIdx.y;                      // 0..31
  const float* p = part + (size_t)g * 32 * S + j;
  double s = 0.0;
  for (int b = 0; b < 32; ++b) s += (double)p[(size_t)b * S];
  accp[(size_t)g * S + j] = s;
}
__global__ void vals2_kernel(const double* __restrict__ accp,
                             double* __restrict__ vals) {
  int j = blockIdx.x * 256 + threadIdx.x;
  double s = 0.0;
  for (int g = 0; g < 32; ++g) s += accp[(size_t)g * S + j];
  vals[j] = s;
}

// 7) Parallel exact rank -> selection flag (tie-break: lower index wins,
//    matching lax.top_k).
__global__ void flags_kernel(const double* __restrict__ vals,
                             int* __restrict__ flags) {
  int j = blockIdx.x * 256 + threadIdx.x;  // 0..2047
  const double v = vals[j];
  int rank = 0;
  for (int j2 = 0; j2 < S; ++j2) {
    const double v2 = vals[j2];
    rank += (v2 > v) || (v2 == v && j2 < j);
  }
  flags[j] = (rank < KLEN) ? 1 : 0;
}

// 8) Compact selected indices (ascending) + write tokens/indices + append S-1.
__global__ __launch_bounds__(1024) void emit_kernel(
    const int* __restrict__ flags, const int* __restrict__ ids,
    int* __restrict__ out) {
  __shared__ int fl[S];
  __shared__ int csum[32];
  __shared__ int cpre[32];
  const int t = threadIdx.x;
  for (int j = t; j < S; j += 1024) fl[j] = flags[j];
  __syncthreads();
  if (t < 32) {
    int s = 0;
    for (int i = 0; i < 64; ++i) s += fl[t * 64 + i];
    csum[t] = s;
  }
  __syncthreads();
  if (t == 0) {
    int run = 0;
    for (int c = 0; c < 32; ++c) { cpre[c] = run; run += csum[c]; }
  }
  __syncthreads();
  for (int j = t; j < S; j += 1024) {
    if (fl[j]) {
      int pos = cpre[j >> 6];
      for (int j2 = j & ~63; j2 < j; ++j2) pos += fl[j2];
      out[pos] = ids[j];            // pruned tokens [0..1023]
      out[KLEN + 1 + pos] = j;      // indices [1025..2048]
    }
  }
  if (t == 0) {
    out[KLEN] = ids[S - 1];
    out[KLEN + 1 + KLEN] = S - 1;
  }
}

// ---------------------------------------------------------------------------
extern "C" void kernel_launch(void* const* d_in, const int* in_sizes, int n_in,
                              void* d_out, int out_size, void* d_ws, size_t ws_size,
                              hipStream_t stream) {
  const int* ids = (const int*)d_in[0];
  const float* embed = (const float*)d_in[1];
  const float* Wq = (const float*)d_in[2];
  const float* Wk = (const float*)d_in[3];
  int* out = (int*)d_out;
  char* ws = (char*)d_ws;
  float* cosT = (float*)(ws + OFF_COS);
  float* sinT = (float*)(ws + OFF_SIN);
  float* qk   = (float*)(ws + OFF_QK);
  float* kT   = (float*)(ws + OFF_KT);
  float* part = (float*)(ws + OFF_PART);
  double* vals = (double*)(ws + OFF_VALS);
  int* flags  = (int*)(ws + OFF_FLAGS);
  double* accp = (double*)(ws + OFF_ACCP);

  trig_kernel<<<256, 256, 0, stream>>>(cosT, sinT);
  proj_gemm<<<dim3(ETOT / BN, S / BM), 128, 0, stream>>>(ids, embed, Wq, Wk, qk);
  rope_q_kernel<<<(S * NH * 32) / 256, 256, 0, stream>>>(qk, cosT, sinT);
  rope_k_kernel<<<dim3(NKV, S / 64), 256, 0, stream>>>(qk, kT, cosT, sinT);
  attn_kernel<<<dim3(NH, 32), 256, 0, stream>>>(qk, kT, part);
  vals1_kernel<<<dim3(S / 256, 32), 256, 0, stream>>>(part, accp);
  vals2_kernel<<<S / 256, 256, 0, stream>>>(accp, vals);
  flags_kernel<<<S / 256, 256, 0, stream>>>(vals, flags);
  emit_kernel<<<1, 1024, 0, stream>>>(flags, ids, out);
}

// Round 4
// 904.713 us; speedup vs baseline: 1.1511x; 1.1511x over previous
//
#include <hip/hip_runtime.h>
#include <math.h>

// Problem constants
#define S       2048
#define D       2048
#define EQ      2048   // N_Q_HEADS * HEAD_DIM
#define EK      512    // N_KV_HEADS * HEAD_DIM
#define ETOT    2560   // EQ + EK
#define NH      32
#define NKV     8
#define HD      64
#define KLEN    1024   // max(S*0.5, 2)

// Workspace layout (byte offsets)
#define OFF_COS   ((size_t)0)                    // [S][32] f32 = 256KB
#define OFF_SIN   ((size_t)(256u << 10))         // 256KB
#define OFF_QK    ((size_t)(1u << 20))           // [S][ETOT] f32 = 20MB
#define OFF_KT    ((size_t)(22u << 20))          // [NKV][64][S] f32 = 4MB
#define OFF_PART  ((size_t)(26u << 20))          // [1024][S] f32 = 8MB
#define OFF_VALS  ((size_t)(34u << 20))          // [S] f64 = 16KB
#define OFF_FLAGS ((size_t)((34u << 20) + (16u << 10)))   // [S] i32 = 8KB
#define OFF_ACCP  ((size_t)((34u << 20) + (32u << 10)))   // [32][S] f64 = 512KB

// ---------------------------------------------------------------------------
// 1) cos/sin tables in fp64 (fp32 arg reduction at pos~2047 gives ~1e-4 error,
//    j-correlated -> would destabilize the topk boundary).
__global__ void trig_kernel(float* __restrict__ cosT, float* __restrict__ sinT) {
  int idx = blockIdx.x * blockDim.x + threadIdx.x;  // S*32 = 65536
  int s = idx >> 5, i = idx & 31;
  double invf = 1.0 / pow(10000.0, (double)i / 32.0);
  double ang = (double)s * invf;
  cosT[idx] = (float)cos(ang);
  sinT[idx] = (float)sin(ang);
}

// ---------------------------------------------------------------------------
// 2) Fused gather + projection GEMM, in-block split-K.
//    Block: 256 threads. Lanes 0-127 accumulate k in [0,1024), lanes 128-255
//    k in [1024,2048), each with its own As/Bs slab and 8x8 microtile over a
//    64(s) x 128(e) tile (LDS 0.5 B/FLOP, balanced vs VALU). Epilogue: upper
//    half writes acc to LDS (swizzled idx*128+th -> conflict-free), lower
//    half adds (C = lo + hi, deterministic) and stores.
//    Grid 20x32 = 640 blocks x 4 waves = 2560 waves (2.5/SIMD).
#define BM 64
#define BN 128
#define BK 16
#define AS_LD 68
#define BS_LD 132
#define HALF_FL (BK * AS_LD + BK * BS_LD)   // 3200 floats per half
__global__ __launch_bounds__(256) void proj_gemm(
    const int* __restrict__ ids, const float* __restrict__ embed,
    const float* __restrict__ Wq, const float* __restrict__ Wk,
    float* __restrict__ C) {
  __shared__ float smem[8192];   // stage: 2x3200 fl; combine: 64x128 fl
  __shared__ int rowid[BM];
  const int t = threadIdx.x;           // 0..255
  const int th = t & 127;
  const int half = t >> 7;             // 0: k-lo, 1: k-hi
  const int koff = half * (D / 2);
  const int col0 = blockIdx.x * BN;    // 20 col blocks
  const int row0 = blockIdx.y * BM;    // 32 row blocks
  const float* Wbase = (col0 < EQ) ? (Wq + (size_t)col0 * D)
                                   : (Wk + (size_t)(col0 - EQ) * D);
  if (t < BM) rowid[t] = ids[row0 + t];
  __syncthreads();

  float* As = smem + half * HALF_FL;       // [BK][AS_LD]
  float* Bs = As + BK * AS_LD;             // [BK][BS_LD]

  // staging: A tile 64x16 = 256 quads / 128 thr -> 2 each
  //          B tile 128x16 = 512 quads / 128 thr -> 4 each
  const int ak  = (th & 3) * 4;        // k quad offset
  const int am0 = th >> 2;             // 0..31
  const int am1 = am0 + 32;            // 32..63
  const float* Arow0 = embed + (size_t)rowid[am0] * D + koff + ak;
  const float* Arow1 = embed + (size_t)rowid[am1] * D + koff + ak;
  const float* Brow  = Wbase + (size_t)(th >> 2) * D + koff + ak;

  const int tm0 = (th >> 4) * 8;       // 8 s-rows
  const int tnA = (th & 15) * 4;       // cols tnA..+3 and tnA+64..+67
  float acc[8][8];
#pragma unroll
  for (int i = 0; i < 8; ++i)
#pragma unroll
    for (int j = 0; j < 8; ++j) acc[i][j] = 0.f;

  float4 a0 = *(const float4*)(Arow0);
  float4 a1 = *(const float4*)(Arow1);
  float4 b0 = *(const float4*)(Brow);
  float4 b1 = *(const float4*)(Brow + 32 * D);
  float4 b2 = *(const float4*)(Brow + 64 * D);
  float4 b3 = *(const float4*)(Brow + 96 * D);
  for (int k0 = 0; k0 < D / 2; k0 += BK) {
    __syncthreads();
    As[(ak + 0) * AS_LD + am0] = a0.x; As[(ak + 1) * AS_LD + am0] = a0.y;
    As[(ak + 2) * AS_LD + am0] = a0.z; As[(ak + 3) * AS_LD + am0] = a0.w;
    As[(ak + 0) * AS_LD + am1] = a1.x; As[(ak + 1) * AS_LD + am1] = a1.y;
    As[(ak + 2) * AS_LD + am1] = a1.z; As[(ak + 3) * AS_LD + am1] = a1.w;
    const int bn = th >> 2;
    Bs[(ak + 0) * BS_LD + bn]      = b0.x; Bs[(ak + 1) * BS_LD + bn]      = b0.y;
    Bs[(ak + 2) * BS_LD + bn]      = b0.z; Bs[(ak + 3) * BS_LD + bn]      = b0.w;
    Bs[(ak + 0) * BS_LD + bn + 32] = b1.x; Bs[(ak + 1) * BS_LD + bn + 32] = b1.y;
    Bs[(ak + 2) * BS_LD + bn + 32] = b1.z; Bs[(ak + 3) * BS_LD + bn + 32] = b1.w;
    Bs[(ak + 0) * BS_LD + bn + 64] = b2.x; Bs[(ak + 1) * BS_LD + bn + 64] = b2.y;
    Bs[(ak + 2) * BS_LD + bn + 64] = b2.z; Bs[(ak + 3) * BS_LD + bn + 64] = b2.w;
    Bs[(ak + 0) * BS_LD + bn + 96] = b3.x; Bs[(ak + 1) * BS_LD + bn + 96] = b3.y;
    Bs[(ak + 2) * BS_LD + bn + 96] = b3.z; Bs[(ak + 3) * BS_LD + bn + 96] = b3.w;
    __syncthreads();
    // prefetch next k-tile within this half (wraps; last values discarded)
    const int kn = (k0 + BK) & (D / 2 - 1);
    a0 = *(const float4*)(Arow0 + kn);
    a1 = *(const float4*)(Arow1 + kn);
    b0 = *(const float4*)(Brow + kn);
    b1 = *(const float4*)(Brow + 32 * D + kn);
    b2 = *(const float4*)(Brow + 64 * D + kn);
    b3 = *(const float4*)(Brow + 96 * D + kn);
#pragma unroll
    for (int kk = 0; kk < BK; ++kk) {
      const float4 alo = *(const float4*)&As[kk * AS_LD + tm0];
      const float4 ahi = *(const float4*)&As[kk * AS_LD + tm0 + 4];
      const float4 blo = *(const float4*)&Bs[kk * BS_LD + tnA];
      const float4 bhi = *(const float4*)&Bs[kk * BS_LD + tnA + 64];
      const float av[8] = {alo.x, alo.y, alo.z, alo.w, ahi.x, ahi.y, ahi.z, ahi.w};
      const float bv[8] = {blo.x, blo.y, blo.z, blo.w, bhi.x, bhi.y, bhi.z, bhi.w};
#pragma unroll
      for (int i = 0; i < 8; ++i)
#pragma unroll
        for (int j = 0; j < 8; ++j) acc[i][j] = fmaf(av[i], bv[j], acc[i][j]);
    }
  }
  // combine halves: C = lo + hi (deterministic), then store from lower half
  __syncthreads();
  if (half) {
#pragma unroll
    for (int i = 0; i < 8; ++i)
#pragma unroll
      for (int j = 0; j < 8; ++j)
        smem[(i * 8 + j) * 128 + th] = acc[i][j];   // lanes->consecutive: no conflicts
  }
  __syncthreads();
  if (!half) {
#pragma unroll
    for (int i = 0; i < 8; ++i) {
#pragma unroll
      for (int j = 0; j < 8; ++j) acc[i][j] += smem[(i * 8 + j) * 128 + th];
      float* dst = C + (size_t)(row0 + tm0 + i) * ETOT + col0;
      *(float4*)(dst + tnA)      = make_float4(acc[i][0], acc[i][1], acc[i][2], acc[i][3]);
      *(float4*)(dst + tnA + 64) = make_float4(acc[i][4], acc[i][5], acc[i][6], acc[i][7]);
    }
  }
}

// ---------------------------------------------------------------------------
// 3) RoPE on q, in place. One thread owns the (i, i+32) pair -> no race.
__global__ void rope_q_kernel(float* __restrict__ qk,
                              const float* __restrict__ cosT,
                              const float* __restrict__ sinT) {
  int idx = blockIdx.x * blockDim.x + threadIdx.x;  // S * NH * 32
  int s = idx >> 10;
  int rem = idx & 1023;
  int h = rem >> 5, i = rem & 31;
  float c = cosT[(s << 5) + i], sn = sinT[(s << 5) + i];
  float* p = qk + (size_t)s * ETOT + h * HD + i;
  float x1 = p[0], x2 = p[32];
  p[0]  = fmaf(x1, c, -x2 * sn);
  p[32] = fmaf(x2, c,  x1 * sn);
}

// 4) RoPE on k -> transposed kT[kv][d][s], via LDS tile so both the qk reads
//    and the kT writes are coalesced 256B rows. Bit-identical kT vs R2/R3.
__global__ __launch_bounds__(256) void rope_k_kernel(
    const float* __restrict__ qk, float* __restrict__ kT,
    const float* __restrict__ cosT, const float* __restrict__ sinT) {
  __shared__ float tile[64][65];
  __shared__ float ct[64][33];
  __shared__ float st[64][33];
  const int kv = blockIdx.x;       // 0..7
  const int s0 = blockIdx.y * 64;  // 0..2047
  const int t = threadIdx.x;
  {
    const int c = t & 63, r = t >> 6;
#pragma unroll
    for (int p = 0; p < 16; ++p)
      tile[r + 4 * p][c] = qk[(size_t)(s0 + r + 4 * p) * ETOT + EQ + kv * HD + c];
  }
  {
    const int i = t & 31, r = t >> 5;
#pragma unroll
    for (int p = 0; p < 8; ++p) {
      ct[r + 8 * p][i] = cosT[(s0 + r + 8 * p) * 32 + i];
      st[r + 8 * p][i] = sinT[(s0 + r + 8 * p) * 32 + i];
    }
  }
  __syncthreads();
  const int s = t & 63, dbase = t >> 6;
#pragma unroll
  for (int p = 0; p < 16; ++p) {
    const int d = dbase + 4 * p;
    float v;
    if (d < 32) {
      const float c = ct[s][d], sn = st[s][d];
      const float x1 = tile[s][d], x2 = tile[s][d + 32];
      v = fmaf(x1, c, -x2 * sn);
    } else {
      const float c = ct[s][d - 32], sn = st[s][d - 32];
      const float x1 = tile[s][d - 32], x2 = tile[s][d];
      v = fmaf(x2, c, x1 * sn);
    }
    kT[(size_t)(kv * HD + d) * S + s0 + s] = v;
  }
}

// ---------------------------------------------------------------------------
// 5) Attention. Same decomposition as R2/R3, but q comes from LDS as
//    ds_read_b64 (2 d's per read) instead of 16 scalar b32/d -> halves the
//    LDS-pipe pressure that capped VALUBusy. FMA order (d, r, u) preserved
//    exactly -> bit-identical output.
__global__ __launch_bounds__(256, 2) void attn_kernel(
    const float* __restrict__ qk, const float* __restrict__ kT,
    float* __restrict__ part) {
  const int h = blockIdx.x;    // 0..31
  const int sb = blockIdx.y;   // 0..31
  const int t = threadIdx.x;
  const float* kTh = kT + (size_t)(h >> 2) * HD * S;
  __shared__ float qlds[16][64];
  __shared__ float wred[4][16];
  float colacc[8];
#pragma unroll
  for (int u = 0; u < 8; ++u) colacc[u] = 0.f;
  const int c0 = t * 8;

  for (int ch = 0; ch < 4; ++ch) {
    const int row0 = sb * 64 + ch * 16;
    __syncthreads();
    {
      const int r = t >> 6, dd = t & 63;
#pragma unroll
      for (int rr = 0; rr < 4; ++rr)
        qlds[r + rr * 4][dd] = qk[(size_t)(row0 + r + rr * 4) * ETOT + h * HD + dd];
    }
    __syncthreads();
    float acc[16][8];
#pragma unroll
    for (int r = 0; r < 16; ++r)
#pragma unroll
      for (int u = 0; u < 8; ++u) acc[r][u] = 0.f;

    for (int d2 = 0; d2 < HD; d2 += 2) {
      const float4 k0a = *(const float4*)(kTh + (size_t)d2 * S + c0);
      const float4 k0b = *(const float4*)(kTh + (size_t)d2 * S + c0 + 4);
      const float4 k1a = *(const float4*)(kTh + (size_t)(d2 + 1) * S + c0);
      const float4 k1b = *(const float4*)(kTh + (size_t)(d2 + 1) * S + c0 + 4);
      float2 q2[16];
#pragma unroll
      for (int r = 0; r < 16; ++r) q2[r] = *(const float2*)&qlds[r][d2];
      {
        const float kv[8] = {k0a.x, k0a.y, k0a.z, k0a.w, k0b.x, k0b.y, k0b.z, k0b.w};
#pragma unroll
        for (int r = 0; r < 16; ++r) {
          const float qd = q2[r].x;
#pragma unroll
          for (int u = 0; u < 8; ++u) acc[r][u] = fmaf(qd, kv[u], acc[r][u]);
        }
      }
      {
        const float kv[8] = {k1a.x, k1a.y, k1a.z, k1a.w, k1b.x, k1b.y, k1b.z, k1b.w};
#pragma unroll
        for (int r = 0; r < 16; ++r) {
          const float qd = q2[r].y;
#pragma unroll
          for (int u = 0; u < 8; ++u) acc[r][u] = fmaf(qd, kv[u], acc[r][u]);
        }
      }
    }
    float p[16];
#pragma unroll
    for (int r = 0; r < 16; ++r) {
      p[r] = 0.f;
#pragma unroll
      for (int u = 0; u < 8; ++u) {
        acc[r][u] = expf(acc[r][u]);
        p[r] += acc[r][u];
      }
    }
#pragma unroll
    for (int off = 32; off > 0; off >>= 1)
#pragma unroll
      for (int r = 0; r < 16; ++r) p[r] += __shfl_xor(p[r], off, 64);
    if ((t & 63) == 0) {
#pragma unroll
      for (int r = 0; r < 16; ++r) wred[t >> 6][r] = p[r];
    }
    __syncthreads();
#pragma unroll
    for (int r = 0; r < 16; ++r) {
      const float Z = wred[0][r] + wred[1][r] + wred[2][r] + wred[3][r];
      const float inv = 1.f / Z;
#pragma unroll
      for (int u = 0; u < 8; ++u) colacc[u] = fmaf(acc[r][u], inv, colacc[u]);
    }
  }
  const int b = h * 32 + sb;
  *(float4*)(part + (size_t)b * S + c0)     = make_float4(colacc[0], colacc[1], colacc[2], colacc[3]);
  *(float4*)(part + (size_t)b * S + c0 + 4) = make_float4(colacc[4], colacc[5], colacc[6], colacc[7]);
}

// ---------------------------------------------------------------------------
// 6) fp64 column totals, two stages (same left-to-right order as R3).
__global__ void vals1_kernel(const float* __restrict__ part,
                             double* __restrict__ accp) {
  int j = blockIdx.x * 256 + threadIdx.x;  // 0..2047
  int g = blockIdx.y;                      // 0..31
  const float* p = part + (size_t)g * 32 * S + j;
  double s = 0.0;
  for (int b = 0; b < 32; ++b) s += (double)p[(size_t)b * S];
  accp[(size_t)g * S + j] = s;
}
__global__ void vals2_kernel(const double* __restrict__ accp,
                             double* __restrict__ vals) {
  int j = blockIdx.x * 256 + threadIdx.x;
  double s = 0.0;
  for (int g = 0; g < 32; ++g) s += accp[(size_t)g * S + j];
  vals[j] = s;
}

// 7) Exact rank, one block per j (was 8 latency-bound blocks). Same predicate
//    (tie-break: lower index wins, matching lax.top_k); deterministic.
__global__ __launch_bounds__(256) void flags_kernel(
    const double* __restrict__ vals, int* __restrict__ flags) {
  const int j = blockIdx.x;       // 0..2047
  const int t = threadIdx.x;
  const double v = vals[j];
  int rank = 0;
  for (int j2 = t; j2 < S; j2 += 256) {
    const double v2 = vals[j2];
    rank += (v2 > v) || (v2 == v && j2 < j);
  }
#pragma unroll
  for (int off = 32; off > 0; off >>= 1) rank += __shfl_xor(rank, off, 64);
  __shared__ int red[4];
  if ((t & 63) == 0) red[t >> 6] = rank;
  __syncthreads();
  if (t == 0)
    flags[j] = ((red[0] + red[1] + red[2] + red[3]) < KLEN) ? 1 : 0;
}

// 8) Compact selected indices (ascending) + write tokens/indices + append S-1.
__global__ __launch_bounds__(1024) void emit_kernel(
    const int* __restrict__ flags, const int* __restrict__ ids,
    int* __restrict__ out) {
  __shared__ int fl[S];
  __shared__ int csum[32];
  __shared__ int cpre[32];
  const int t = threadIdx.x;
  for (int j = t; j < S; j += 1024) fl[j] = flags[j];
  __syncthreads();
  if (t < 32) {
    int s = 0;
    for (int i = 0; i < 64; ++i) s += fl[t * 64 + i];
    csum[t] = s;
  }
  __syncthreads();
  if (t == 0) {
    int run = 0;
    for (int c = 0; c < 32; ++c) { cpre[c] = run; run += csum[c]; }
  }
  __syncthreads();
  for (int j = t; j < S; j += 1024) {
    if (fl[j]) {
      int pos = cpre[j >> 6];
      for (int j2 = j & ~63; j2 < j; ++j2) pos += fl[j2];
      out[pos] = ids[j];            // pruned tokens [0..1023]
      out[KLEN + 1 + pos] = j;      // indices [1025..2048]
    }
  }
  if (t == 0) {
    out[KLEN] = ids[S - 1];
    out[KLEN + 1 + KLEN] = S - 1;
  }
}

// ---------------------------------------------------------------------------
extern "C" void kernel_launch(void* const* d_in, const int* in_sizes, int n_in,
                              void* d_out, int out_size, void* d_ws, size_t ws_size,
                              hipStream_t stream) {
  const int* ids = (const int*)d_in[0];
  const float* embed = (const float*)d_in[1];
  const float* Wq = (const float*)d_in[2];
  const float* Wk = (const float*)d_in[3];
  int* out = (int*)d_out;
  char* ws = (char*)d_ws;
  float* cosT = (float*)(ws + OFF_COS);
  float* sinT = (float*)(ws + OFF_SIN);
  float* qk   = (float*)(ws + OFF_QK);
  float* kT   = (float*)(ws + OFF_KT);
  float* part = (float*)(ws + OFF_PART);
  double* vals = (double*)(ws + OFF_VALS);
  int* flags  = (int*)(ws + OFF_FLAGS);
  double* accp = (double*)(ws + OFF_ACCP);

  trig_kernel<<<256, 256, 0, stream>>>(cosT, sinT);
  proj_gemm<<<dim3(ETOT / BN, S / BM), 256, 0, stream>>>(ids, embed, Wq, Wk, qk);
  rope_q_kernel<<<(S * NH * 32) / 256, 256, 0, stream>>>(qk, cosT, sinT);
  rope_k_kernel<<<dim3(NKV, S / 64), 256, 0, stream>>>(qk, kT, cosT, sinT);
  attn_kernel<<<dim3(NH, 32), 256, 0, stream>>>(qk, kT, part);
  vals1_kernel<<<dim3(S / 256, 32), 256, 0, stream>>>(part, accp);
  vals2_kernel<<<S / 256, 256, 0, stream>>>(accp, vals);
  flags_kernel<<<S, 256, 0, stream>>>(vals, flags);
  emit_kernel<<<1, 1024, 0, stream>>>(flags, ids, out);
}

// Round 5
// 866.561 us; speedup vs baseline: 1.2017x; 1.0440x over previous
//
#include <hip/hip_runtime.h>
#include <math.h>

// Problem constants
#define S       2048
#define D       2048
#define EQ      2048   // N_Q_HEADS * HEAD_DIM
#define EK      512    // N_KV_HEADS * HEAD_DIM
#define ETOT    2560   // EQ + EK
#define NH      32
#define NKV     8
#define HD      64
#define KLEN    1024   // max(S*0.5, 2)

// Workspace layout (byte offsets)
#define OFF_COS   ((size_t)0)                    // [S][32] f32 = 256KB
#define OFF_SIN   ((size_t)(256u << 10))         // 256KB
#define OFF_QK    ((size_t)(1u << 20))           // [S][ETOT] f32 = 20MB
#define OFF_KT    ((size_t)(22u << 20))          // [NKV][64][S] f32 = 4MB
#define OFF_PART  ((size_t)(26u << 20))          // [1024][S] f32 = 8MB
#define OFF_VALS  ((size_t)(34u << 20))          // [S] f64 = 16KB
#define OFF_FLAGS ((size_t)((34u << 20) + (16u << 10)))   // [S] i32 = 8KB
#define OFF_ACCP  ((size_t)((34u << 20) + (32u << 10)))   // [32][S] f64 = 512KB

// ---------------------------------------------------------------------------
// 1) cos/sin tables in fp64 (fp32 arg reduction at pos~2047 gives ~1e-4 error,
//    j-correlated -> would destabilize the topk boundary).
__global__ void trig_kernel(float* __restrict__ cosT, float* __restrict__ sinT) {
  int idx = blockIdx.x * blockDim.x + threadIdx.x;  // S*32 = 65536
  int s = idx >> 5, i = idx & 31;
  double invf = 1.0 / pow(10000.0, (double)i / 32.0);
  double ang = (double)s * invf;
  cosT[idx] = (float)cos(ang);
  sinT[idx] = (float)sin(ang);
}

// ---------------------------------------------------------------------------
// 2) Fused gather + projection GEMM: C[s][e] = sum_d embed[ids[s]][d]*W[e][d].
//    64x64 tile, BK=16, 128 threads, 8(m)x4(n) microtile, NO split-K.
//    Waves: 1280 blocks x 2 = 2560 (exactly 5 blocks/CU, no tail).
//    LDS reads/wave/kk: As 2xb128 over 4 unique addrs (16-way broadcast,
//    cheap) + Bs 1xb128 over 16 unique addrs spanning all 32 banks 2-way
//    (free). 32 FMA-inst/kk vs R2's 16 at same read count -> ratio 2x R2.
//    Per-element k-accumulation order identical to R1-R4 (bit-stable).
#define BM 64
#define BN 64
#define BK 16
__global__ __launch_bounds__(128) void proj_gemm(
    const int* __restrict__ ids, const float* __restrict__ embed,
    const float* __restrict__ Wq, const float* __restrict__ Wk,
    float* __restrict__ C) {
  __shared__ float As[BK][BM + 4];   // 16 x 68
  __shared__ float Bs[BK][BN + 4];
  __shared__ int rowid[BM];
  const int t = threadIdx.x;           // 0..127
  const int col0 = blockIdx.x * BN;    // 40 col blocks
  const int row0 = blockIdx.y * BM;    // 32 row blocks
  const float* Wbase = (col0 < EQ) ? (Wq + (size_t)col0 * D)
                                   : (Wk + (size_t)(col0 - EQ) * D);
  if (t < BM) rowid[t] = ids[row0 + t];
  __syncthreads();

  // staging: A tile 64x16 = 256 quads / 128 thr -> 2 each; B same.
  const int ak  = (t & 3) * 4;       // k quad offset
  const int am0 = t >> 2;            // 0..31
  const int am1 = am0 + 32;          // 32..63
  const float* Arow0 = embed + (size_t)rowid[am0] * D + ak;
  const float* Arow1 = embed + (size_t)rowid[am1] * D + ak;
  const float* Brow0 = Wbase + (size_t)am0 * D + ak;
  const float* Brow1 = Wbase + (size_t)am1 * D + ak;

  const int tm0 = (t >> 4) * 8;      // 8 s-rows
  const int tn0 = (t & 15) * 4;      // 4 e-cols
  float acc[8][4];
#pragma unroll
  for (int i = 0; i < 8; ++i)
#pragma unroll
    for (int j = 0; j < 4; ++j) acc[i][j] = 0.f;

  float4 a0 = *(const float4*)(Arow0);
  float4 a1 = *(const float4*)(Arow1);
  float4 b0 = *(const float4*)(Brow0);
  float4 b1 = *(const float4*)(Brow1);
  for (int k0 = 0; k0 < D; k0 += BK) {
    __syncthreads();
    As[ak + 0][am0] = a0.x; As[ak + 1][am0] = a0.y;
    As[ak + 2][am0] = a0.z; As[ak + 3][am0] = a0.w;
    As[ak + 0][am1] = a1.x; As[ak + 1][am1] = a1.y;
    As[ak + 2][am1] = a1.z; As[ak + 3][am1] = a1.w;
    Bs[ak + 0][am0] = b0.x; Bs[ak + 1][am0] = b0.y;
    Bs[ak + 2][am0] = b0.z; Bs[ak + 3][am0] = b0.w;
    Bs[ak + 0][am1] = b1.x; Bs[ak + 1][am1] = b1.y;
    Bs[ak + 2][am1] = b1.z; Bs[ak + 3][am1] = b1.w;
    __syncthreads();
    // prefetch next k-tile (wraps on last iter; values discarded)
    const int kn = (k0 + BK) & (D - 1);
    a0 = *(const float4*)(Arow0 + kn);
    a1 = *(const float4*)(Arow1 + kn);
    b0 = *(const float4*)(Brow0 + kn);
    b1 = *(const float4*)(Brow1 + kn);
#pragma unroll
    for (int kk = 0; kk < BK; ++kk) {
      const float4 alo = *(const float4*)&As[kk][tm0];
      const float4 ahi = *(const float4*)&As[kk][tm0 + 4];
      const float4 bv  = *(const float4*)&Bs[kk][tn0];
      const float av[8] = {alo.x, alo.y, alo.z, alo.w, ahi.x, ahi.y, ahi.z, ahi.w};
#pragma unroll
      for (int i = 0; i < 8; ++i) {
        acc[i][0] = fmaf(av[i], bv.x, acc[i][0]);
        acc[i][1] = fmaf(av[i], bv.y, acc[i][1]);
        acc[i][2] = fmaf(av[i], bv.z, acc[i][2]);
        acc[i][3] = fmaf(av[i], bv.w, acc[i][3]);
      }
    }
  }
#pragma unroll
  for (int i = 0; i < 8; ++i) {
    float* dst = C + (size_t)(row0 + tm0 + i) * ETOT + col0 + tn0;
    *(float4*)dst = make_float4(acc[i][0], acc[i][1], acc[i][2], acc[i][3]);
  }
}

// ---------------------------------------------------------------------------
// 3) RoPE on q, in place. One thread owns the (i, i+32) pair -> no race.
__global__ void rope_q_kernel(float* __restrict__ qk,
                              const float* __restrict__ cosT,
                              const float* __restrict__ sinT) {
  int idx = blockIdx.x * blockDim.x + threadIdx.x;  // S * NH * 32
  int s = idx >> 10;
  int rem = idx & 1023;
  int h = rem >> 5, i = rem & 31;
  float c = cosT[(s << 5) + i], sn = sinT[(s << 5) + i];
  float* p = qk + (size_t)s * ETOT + h * HD + i;
  float x1 = p[0], x2 = p[32];
  p[0]  = fmaf(x1, c, -x2 * sn);
  p[32] = fmaf(x2, c,  x1 * sn);
}

// 4) RoPE on k -> transposed kT[kv][d][s], via LDS tile so both the qk reads
//    and the kT writes are coalesced 256B rows. Bit-identical kT vs R2-R4.
__global__ __launch_bounds__(256) void rope_k_kernel(
    const float* __restrict__ qk, float* __restrict__ kT,
    const float* __restrict__ cosT, const float* __restrict__ sinT) {
  __shared__ float tile[64][65];
  __shared__ float ct[64][33];
  __shared__ float st[64][33];
  const int kv = blockIdx.x;       // 0..7
  const int s0 = blockIdx.y * 64;  // 0..2047
  const int t = threadIdx.x;
  {
    const int c = t & 63, r = t >> 6;
#pragma unroll
    for (int p = 0; p < 16; ++p)
      tile[r + 4 * p][c] = qk[(size_t)(s0 + r + 4 * p) * ETOT + EQ + kv * HD + c];
  }
  {
    const int i = t & 31, r = t >> 5;
#pragma unroll
    for (int p = 0; p < 8; ++p) {
      ct[r + 8 * p][i] = cosT[(s0 + r + 8 * p) * 32 + i];
      st[r + 8 * p][i] = sinT[(s0 + r + 8 * p) * 32 + i];
    }
  }
  __syncthreads();
  const int s = t & 63, dbase = t >> 6;
#pragma unroll
  for (int p = 0; p < 16; ++p) {
    const int d = dbase + 4 * p;
    float v;
    if (d < 32) {
      const float c = ct[s][d], sn = st[s][d];
      const float x1 = tile[s][d], x2 = tile[s][d + 32];
      v = fmaf(x1, c, -x2 * sn);
    } else {
      const float c = ct[s][d - 32], sn = st[s][d - 32];
      const float x1 = tile[s][d - 32], x2 = tile[s][d];
      v = fmaf(x2, c, x1 * sn);
    }
    kT[(size_t)(kv * HD + d) * S + s0 + s] = v;
  }
}

// ---------------------------------------------------------------------------
// 5) Attention. R4 structure, two fixes: (a) dropped the min-waves launch
//    bound (acc[16][8]+q2+k-regs ~200 VGPR; the (256,2) cap risked spills),
//    (b) restored one-deep prefetch on the d2-loop (dependent L2 loads
//    otherwise serialize). FMA order (d, r, u) preserved -> bit-identical.
__global__ __launch_bounds__(256) void attn_kernel(
    const float* __restrict__ qk, const float* __restrict__ kT,
    float* __restrict__ part) {
  const int h = blockIdx.x;    // 0..31
  const int sb = blockIdx.y;   // 0..31
  const int t = threadIdx.x;
  const float* kTh = kT + (size_t)(h >> 2) * HD * S;
  __shared__ float qlds[16][64];
  __shared__ float wred[4][16];
  float colacc[8];
#pragma unroll
  for (int u = 0; u < 8; ++u) colacc[u] = 0.f;
  const int c0 = t * 8;

  for (int ch = 0; ch < 4; ++ch) {
    const int row0 = sb * 64 + ch * 16;
    __syncthreads();
    {
      const int r = t >> 6, dd = t & 63;
#pragma unroll
      for (int rr = 0; rr < 4; ++rr)
        qlds[r + rr * 4][dd] = qk[(size_t)(row0 + r + rr * 4) * ETOT + h * HD + dd];
    }
    __syncthreads();
    float acc[16][8];
#pragma unroll
    for (int r = 0; r < 16; ++r)
#pragma unroll
      for (int u = 0; u < 8; ++u) acc[r][u] = 0.f;

    float4 c0a = *(const float4*)(kTh + c0);
    float4 c0b = *(const float4*)(kTh + c0 + 4);
    float4 c1a = *(const float4*)(kTh + (size_t)S + c0);
    float4 c1b = *(const float4*)(kTh + (size_t)S + c0 + 4);
    for (int d2 = 0; d2 < HD; d2 += 2) {
      const int dn = (d2 + 2) & (HD - 1);   // wrap; last prefetch discarded
      const float4 n0a = *(const float4*)(kTh + (size_t)dn * S + c0);
      const float4 n0b = *(const float4*)(kTh + (size_t)dn * S + c0 + 4);
      const float4 n1a = *(const float4*)(kTh + (size_t)(dn + 1) * S + c0);
      const float4 n1b = *(const float4*)(kTh + (size_t)(dn + 1) * S + c0 + 4);
      float2 q2[16];
#pragma unroll
      for (int r = 0; r < 16; ++r) q2[r] = *(const float2*)&qlds[r][d2];
      {
        const float kv[8] = {c0a.x, c0a.y, c0a.z, c0a.w, c0b.x, c0b.y, c0b.z, c0b.w};
#pragma unroll
        for (int r = 0; r < 16; ++r) {
          const float qd = q2[r].x;
#pragma unroll
          for (int u = 0; u < 8; ++u) acc[r][u] = fmaf(qd, kv[u], acc[r][u]);
        }
      }
      {
        const float kv[8] = {c1a.x, c1a.y, c1a.z, c1a.w, c1b.x, c1b.y, c1b.z, c1b.w};
#pragma unroll
        for (int r = 0; r < 16; ++r) {
          const float qd = q2[r].y;
#pragma unroll
          for (int u = 0; u < 8; ++u) acc[r][u] = fmaf(qd, kv[u], acc[r][u]);
        }
      }
      c0a = n0a; c0b = n0b; c1a = n1a; c1b = n1b;
    }
    float p[16];
#pragma unroll
    for (int r = 0; r < 16; ++r) {
      p[r] = 0.f;
#pragma unroll
      for (int u = 0; u < 8; ++u) {
        acc[r][u] = expf(acc[r][u]);
        p[r] += acc[r][u];
      }
    }
#pragma unroll
    for (int off = 32; off > 0; off >>= 1)
#pragma unroll
      for (int r = 0; r < 16; ++r) p[r] += __shfl_xor(p[r], off, 64);
    if ((t & 63) == 0) {
#pragma unroll
      for (int r = 0; r < 16; ++r) wred[t >> 6][r] = p[r];
    }
    __syncthreads();
#pragma unroll
    for (int r = 0; r < 16; ++r) {
      const float Z = wred[0][r] + wred[1][r] + wred[2][r] + wred[3][r];
      const float inv = 1.f / Z;
#pragma unroll
      for (int u = 0; u < 8; ++u) colacc[u] = fmaf(acc[r][u], inv, colacc[u]);
    }
  }
  const int b = h * 32 + sb;
  *(float4*)(part + (size_t)b * S + c0)     = make_float4(colacc[0], colacc[1], colacc[2], colacc[3]);
  *(float4*)(part + (size_t)b * S + c0 + 4) = make_float4(colacc[4], colacc[5], colacc[6], colacc[7]);
}

// ---------------------------------------------------------------------------
// 6) fp64 column totals, two stages (same left-to-right order as R3/R4).
__global__ void vals1_kernel(const float* __restrict__ part,
                             double* __restrict__ accp) {
  int j = blockIdx.x * 256 + threadIdx.x;  // 0..2047
  int g = blockIdx.y;                      // 0..31
  const float* p = part + (size_t)g * 32 * S + j;
  double s = 0.0;
  for (int b = 0; b < 32; ++b) s += (double)p[(size_t)b * S];
  accp[(size_t)g * S + j] = s;
}
__global__ void vals2_kernel(const double* __restrict__ accp,
                             double* __restrict__ vals) {
  int j = blockIdx.x * 256 + threadIdx.x;
  double s = 0.0;
  for (int g = 0; g < 32; ++g) s += accp[(size_t)g * S + j];
  vals[j] = s;
}

// 7) Exact rank, one block per j. Same predicate (tie-break: lower index
//    wins, matching lax.top_k); deterministic.
__global__ __launch_bounds__(256) void flags_kernel(
    const double* __restrict__ vals, int* __restrict__ flags) {
  const int j = blockIdx.x;       // 0..2047
  const int t = threadIdx.x;
  const double v = vals[j];
  int rank = 0;
  for (int j2 = t; j2 < S; j2 += 256) {
    const double v2 = vals[j2];
    rank += (v2 > v) || (v2 == v && j2 < j);
  }
#pragma unroll
  for (int off = 32; off > 0; off >>= 1) rank += __shfl_xor(rank, off, 64);
  __shared__ int red[4];
  if ((t & 63) == 0) red[t >> 6] = rank;
  __syncthreads();
  if (t == 0)
    flags[j] = ((red[0] + red[1] + red[2] + red[3]) < KLEN) ? 1 : 0;
}

// 8) Compact selected indices (ascending) + write tokens/indices + append S-1.
__global__ __launch_bounds__(1024) void emit_kernel(
    const int* __restrict__ flags, const int* __restrict__ ids,
    int* __restrict__ out) {
  __shared__ int fl[S];
  __shared__ int csum[32];
  __shared__ int cpre[32];
  const int t = threadIdx.x;
  for (int j = t; j < S; j += 1024) fl[j] = flags[j];
  __syncthreads();
  if (t < 32) {
    int s = 0;
    for (int i = 0; i < 64; ++i) s += fl[t * 64 + i];
    csum[t] = s;
  }
  __syncthreads();
  if (t == 0) {
    int run = 0;
    for (int c = 0; c < 32; ++c) { cpre[c] = run; run += csum[c]; }
  }
  __syncthreads();
  for (int j = t; j < S; j += 1024) {
    if (fl[j]) {
      int pos = cpre[j >> 6];
      for (int j2 = j & ~63; j2 < j; ++j2) pos += fl[j2];
      out[pos] = ids[j];            // pruned tokens [0..1023]
      out[KLEN + 1 + pos] = j;      // indices [1025..2048]
    }
  }
  if (t == 0) {
    out[KLEN] = ids[S - 1];
    out[KLEN + 1 + KLEN] = S - 1;
  }
}

// ---------------------------------------------------------------------------
extern "C" void kernel_launch(void* const* d_in, const int* in_sizes, int n_in,
                              void* d_out, int out_size, void* d_ws, size_t ws_size,
                              hipStream_t stream) {
  const int* ids = (const int*)d_in[0];
  const float* embed = (const float*)d_in[1];
  const float* Wq = (const float*)d_in[2];
  const float* Wk = (const float*)d_in[3];
  int* out = (int*)d_out;
  char* ws = (char*)d_ws;
  float* cosT = (float*)(ws + OFF_COS);
  float* sinT = (float*)(ws + OFF_SIN);
  float* qk   = (float*)(ws + OFF_QK);
  float* kT   = (float*)(ws + OFF_KT);
  float* part = (float*)(ws + OFF_PART);
  double* vals = (double*)(ws + OFF_VALS);
  int* flags  = (int*)(ws + OFF_FLAGS);
  double* accp = (double*)(ws + OFF_ACCP);

  trig_kernel<<<256, 256, 0, stream>>>(cosT, sinT);
  proj_gemm<<<dim3(ETOT / BN, S / BM), 128, 0, stream>>>(ids, embed, Wq, Wk, qk);
  rope_q_kernel<<<(S * NH * 32) / 256, 256, 0, stream>>>(qk, cosT, sinT);
  rope_k_kernel<<<dim3(NKV, S / 64), 256, 0, stream>>>(qk, kT, cosT, sinT);
  attn_kernel<<<dim3(NH, 32), 256, 0, stream>>>(qk, kT, part);
  vals1_kernel<<<dim3(S / 256, 32), 256, 0, stream>>>(part, accp);
  vals2_kernel<<<S / 256, 256, 0, stream>>>(accp, vals);
  flags_kernel<<<S, 256, 0, stream>>>(vals, flags);
  emit_kernel<<<1, 1024, 0, stream>>>(flags, ids, out);
}